// Round 5
// baseline (335.959 us; speedup 1.0000x reference)
//
#include <hip/hip_runtime.h>

// CCE loss reduction: out[0] = -sum(input * log(target + 1e-8)) / B
// B = 262144, C = 128, f32. 268 MB read-once -> memory-bound, ~43 us floor.
// R1: simple loop, VGPR=12 -> 104 us (2.58 TB/s effective).
// R2: 4x unroll -> compiler re-serialized (VGPR=32) -> 104 us.
// R4: ping-pong + sched_barrier(0) + launch_bounds(256,2) -> STILL VGPR=32,
//     still 104 us. Time invariant across 3 structures => wave-ILP theory
//     is suspect. Little's law says 2 loads/wave x 19 waves/CU should already
//     saturate HBM; implied latency ~9000cy => memory system itself limiting?
// R5: DISCRIMINATOR. Main kernel (simple R1 structure, known 104 us) + a
//     pure-read probe (same pattern, no log) writing to d_ws. If probe ~104us
//     -> pattern/machine ceiling (attack layout next). If probe ~50us ->
//     compute/codegen throttles issue (attack kernel structure next).

constexpr int BLOCK = 256;
constexpr int GRID  = 2048;  // 8 blocks/CU x 256 CUs

__global__ __launch_bounds__(BLOCK) void cce_main_kernel(
    const float* __restrict__ inp, const float* __restrict__ tgt,
    float* __restrict__ out, int n4, float neg_inv_b) {
  const float4* __restrict__ in4 = reinterpret_cast<const float4*>(inp);
  const float4* __restrict__ tg4 = reinterpret_cast<const float4*>(tgt);

  const int idx    = blockIdx.x * BLOCK + threadIdx.x;
  const int stride = GRID * BLOCK;

  float a0 = 0.0f, a1 = 0.0f;
  for (int i = idx; i < n4; i += stride) {
    float4 x = in4[i];
    float4 y = tg4[i];
    a0 += x.x * __logf(y.x + 1e-8f);
    a1 += x.y * __logf(y.y + 1e-8f);
    a0 += x.z * __logf(y.z + 1e-8f);
    a1 += x.w * __logf(y.w + 1e-8f);
  }
  float acc = a0 + a1;

  #pragma unroll
  for (int off = 32; off > 0; off >>= 1)
    acc += __shfl_down(acc, off, 64);

  __shared__ float s[BLOCK / 64];
  const int lane = threadIdx.x & 63;
  const int wave = threadIdx.x >> 6;
  if (lane == 0) s[wave] = acc;
  __syncthreads();

  if (threadIdx.x == 0) {
    float t = 0.0f;
    #pragma unroll
    for (int w = 0; w < BLOCK / 64; ++w) t += s[w];
    atomicAdd(out, t * neg_inv_b);
  }
}

// Pure-read bandwidth probe: identical grid/pattern/streams, no transcendental.
// Result goes to d_ws (never validated) just to keep the loads alive.
__global__ __launch_bounds__(BLOCK) void bw_probe_kernel(
    const float* __restrict__ inp, const float* __restrict__ tgt,
    float* __restrict__ ws, int n4) {
  const float4* __restrict__ in4 = reinterpret_cast<const float4*>(inp);
  const float4* __restrict__ tg4 = reinterpret_cast<const float4*>(tgt);

  const int idx    = blockIdx.x * BLOCK + threadIdx.x;
  const int stride = GRID * BLOCK;

  float acc = 0.0f;
  for (int i = idx; i < n4; i += stride) {
    float4 x = in4[i];
    float4 y = tg4[i];
    acc += (x.x + x.y) + (x.z + x.w) + (y.x + y.y) + (y.z + y.w);
  }

  #pragma unroll
  for (int off = 32; off > 0; off >>= 1)
    acc += __shfl_down(acc, off, 64);

  __shared__ float s[BLOCK / 64];
  const int lane = threadIdx.x & 63;
  const int wave = threadIdx.x >> 6;
  if (lane == 0) s[wave] = acc;
  __syncthreads();

  if (threadIdx.x == 0) {
    float t = 0.0f;
    #pragma unroll
    for (int w = 0; w < BLOCK / 64; ++w) t += s[w];
    atomicAdd(ws, t);  // d_ws scratch; never validated
  }
}

extern "C" void kernel_launch(void* const* d_in, const int* in_sizes, int n_in,
                              void* d_out, int out_size, void* d_ws, size_t ws_size,
                              hipStream_t stream) {
  const float* inp = reinterpret_cast<const float*>(d_in[0]);
  const float* tgt = reinterpret_cast<const float*>(d_in[1]);
  float* out = reinterpret_cast<float*>(d_out);

  const long long n = (long long)in_sizes[0];  // 262144 * 128
  const int n4 = (int)(n / 4);
  const long long B = 262144;                  // rows, per reference
  const float neg_inv_b = -1.0f / (float)B;

  // d_out re-poisoned to 0xAA before every timed launch -> zero it here.
  (void)hipMemsetAsync(d_out, 0, out_size * sizeof(float), stream);

  cce_main_kernel<<<GRID, BLOCK, 0, stream>>>(inp, tgt, out, n4, neg_inv_b);

  // Diagnostic probe (same work every call -> graph-capture safe).
  if (ws_size >= sizeof(float)) {
    bw_probe_kernel<<<GRID, BLOCK, 0, stream>>>(inp, tgt, (float*)d_ws, n4);
  }
}

// Round 6
// 284.681 us; speedup vs baseline: 1.1801x; 1.1801x over previous
//
#include <hip/hip_runtime.h>

// CCE loss reduction: out[0] = -sum(input * log(target + 1e-8)) / B
// B = 262144, C = 128, f32. 268 MB read-once -> memory-bound, ~43 us floor.
// R1: simple loop, VGPR=12 -> 104 us (2.58 TB/s effective).
// R2/R4: source-level unroll + sched_barrier + launch_bounds -> backend
//        collapsed both (VGPR 32): still 104 us. Compiler won't keep >2
//        loads in flight from HIP source.
// R5: pure-read probe (same pattern, atomics included) ran ~57 us @4.7 TB/s
//     -> machine can stream 2x faster; atomic tail <=15 us (exonerated);
//     main is latency x depth bound (period ~10K cyc, depth 2).
// R6: force depth=8 with INLINE ASM: 8x global_load_dwordx4 + single
//     s_waitcnt vmcnt(0) inside one asm block, early-clobber outputs.
//     Log path and atomic unchanged (one variable: load depth).

typedef float f32x4 __attribute__((ext_vector_type(4)));

constexpr int BLOCK = 256;
constexpr int GRID  = 2048;   // 8 blocks/CU x 256 CUs
constexpr int ITERS = 16;     // float4s per thread at the benched shape

__device__ __forceinline__ void accum4(const f32x4& u, const f32x4& v,
                                       float& a0, float& a1) {
  a0 += u[0] * __logf(v[0] + 1e-8f);
  a1 += u[1] * __logf(v[1] + 1e-8f);
  a0 += u[2] * __logf(v[2] + 1e-8f);
  a1 += u[3] * __logf(v[3] + 1e-8f);
}

__global__ __launch_bounds__(BLOCK) void cce_kernel(
    const float* __restrict__ inp, const float* __restrict__ tgt,
    float* __restrict__ out, int n4, float neg_inv_b) {
  const f32x4* __restrict__ A = reinterpret_cast<const f32x4*>(inp);
  const f32x4* __restrict__ T = reinterpret_cast<const f32x4*>(tgt);

  const int tid    = blockIdx.x * BLOCK + threadIdx.x;
  const int stride = GRID * BLOCK;

  float a0 = 0.0f, a1 = 0.0f;

  if (n4 == stride * ITERS) {
    // Static path: 4 batches; each batch = 8 loads in flight (ISA-guaranteed).
    #pragma unroll
    for (int b = 0; b < 4; ++b) {
      const int i = tid + b * 4 * stride;
      const f32x4* pa0 = A + i;
      const f32x4* pa1 = A + i + stride;
      const f32x4* pa2 = A + i + 2 * stride;
      const f32x4* pa3 = A + i + 3 * stride;
      const f32x4* pb0 = T + i;
      const f32x4* pb1 = T + i + stride;
      const f32x4* pb2 = T + i + 2 * stride;
      const f32x4* pb3 = T + i + 3 * stride;

      f32x4 x0, x1, x2, x3, y0, y1, y2, y3;
      asm volatile(
          "global_load_dwordx4 %[x0], %[a0], off\n\t"
          "global_load_dwordx4 %[y0], %[b0], off\n\t"
          "global_load_dwordx4 %[x1], %[a1], off\n\t"
          "global_load_dwordx4 %[y1], %[b1], off\n\t"
          "global_load_dwordx4 %[x2], %[a2], off\n\t"
          "global_load_dwordx4 %[y2], %[b2], off\n\t"
          "global_load_dwordx4 %[x3], %[a3], off\n\t"
          "global_load_dwordx4 %[y3], %[b3], off\n\t"
          "s_waitcnt vmcnt(0)"
          : [x0] "=&v"(x0), [x1] "=&v"(x1), [x2] "=&v"(x2), [x3] "=&v"(x3),
            [y0] "=&v"(y0), [y1] "=&v"(y1), [y2] "=&v"(y2), [y3] "=&v"(y3)
          : [a0] "v"(pa0), [a1] "v"(pa1), [a2] "v"(pa2), [a3] "v"(pa3),
            [b0] "v"(pb0), [b1] "v"(pb1), [b2] "v"(pb2), [b3] "v"(pb3)
          : "memory");

      accum4(x0, y0, a0, a1);
      accum4(x1, y1, a0, a1);
      accum4(x2, y2, a0, a1);
      accum4(x3, y3, a0, a1);
    }
  } else {
    // Generic fallback (not taken at the benched shape).
    for (int i = tid; i < n4; i += stride) {
      f32x4 u = A[i];
      f32x4 v = T[i];
      accum4(u, v, a0, a1);
    }
  }

  float acc = a0 + a1;

  // wave-64 shuffle reduction
  #pragma unroll
  for (int off = 32; off > 0; off >>= 1)
    acc += __shfl_down(acc, off, 64);

  __shared__ float s[BLOCK / 64];
  const int lane = threadIdx.x & 63;
  const int wave = threadIdx.x >> 6;
  if (lane == 0) s[wave] = acc;
  __syncthreads();

  if (threadIdx.x == 0) {
    float t = 0.0f;
    #pragma unroll
    for (int w = 0; w < BLOCK / 64; ++w) t += s[w];
    atomicAdd(out, t * neg_inv_b);  // proven <=15us tail in R5
  }
}

extern "C" void kernel_launch(void* const* d_in, const int* in_sizes, int n_in,
                              void* d_out, int out_size, void* d_ws, size_t ws_size,
                              hipStream_t stream) {
  const float* inp = reinterpret_cast<const float*>(d_in[0]);
  const float* tgt = reinterpret_cast<const float*>(d_in[1]);
  float* out = reinterpret_cast<float*>(d_out);

  const long long n = (long long)in_sizes[0];  // 262144 * 128
  const int n4 = (int)(n / 4);
  const long long B = 262144;                  // rows, per reference
  const float neg_inv_b = -1.0f / (float)B;

  // d_out re-poisoned to 0xAA before every timed launch -> zero it here.
  (void)hipMemsetAsync(d_out, 0, out_size * sizeof(float), stream);

  cce_kernel<<<GRID, BLOCK, 0, stream>>>(inp, tgt, out, n4, neg_inv_b);
}